// Round 9
// baseline (255.228 us; speedup 1.0000x reference)
//
#include <hip/hip_runtime.h>

// Problem constants
#define NB 16
#define NH 96
#define NW 320
#define NCIN 32

#define FC_K 61440
#define FC_KB 128          // k per block (4 phases x 32)
#define FC_NKC 480         // 61440/128 chunks

typedef __attribute__((ext_vector_type(8))) short short8;     // 8 bf16 (4 VGPRs)
typedef __attribute__((ext_vector_type(4))) float f32x4;

__device__ inline unsigned short f2bf(float f) {
    union { float f; unsigned int u; } v; v.f = f;
    unsigned int r = v.u + 0x7FFF + ((v.u >> 16) & 1);   // RNE
    return (unsigned short)(r >> 16);
}
__device__ inline float bf2f(unsigned short s) {
    union { unsigned int u; float f; } v; v.u = ((unsigned int)s) << 16; return v.f;
}
__device__ inline unsigned short fhi(float f) {        // exact for bf16-valued floats
    union { float f; unsigned int u; } v; v.f = f; return (unsigned short)(v.u >> 16);
}

// Async global->LDS 16B DMA: no destination VGPR exists, so the compiler
// cannot sink/split/reissue it (the R3/R7/R8 register-preload failure mode
// is structurally impossible). LDS dest must be wave-uniform base + lane*16.
__device__ inline void gload_lds16(const float* gsrc, float* lds_dst) {
    __builtin_amdgcn_global_load_lds(
        (const __attribute__((address_space(1))) unsigned int*)gsrc,
        (__attribute__((address_space(3))) unsigned int*)lds_dst, 16, 0, 0);
}

// ---------------------------------------------------------------------------
// Fused setup kernel (unchanged): wfrag prep + scatter-cast of active cells.
// ---------------------------------------------------------------------------
__global__ __launch_bounds__(256) void setup_all(const float* __restrict__ w1,
                                                 const float* __restrict__ w2,
                                                 const float* __restrict__ w3,
                                                 unsigned short* __restrict__ f1,
                                                 unsigned short* __restrict__ f2,
                                                 unsigned short* __restrict__ f3,
                                                 const int* __restrict__ coords,
                                                 const float* __restrict__ input,
                                                 unsigned short* __restrict__ inBf,
                                                 int n) {
    if (blockIdx.x < 396) {
        int i = blockIdx.x * 256 + threadIdx.x;
        if (i < 9216) {                       // conv1: IC=32 OC=32 NT=2 KS=1
            int j = i & 7, lane = (i >> 3) & 63, nt = (i >> 9) & 1, tap = i >> 10;
            int ic = ((lane >> 4) * 8) + j, oc = nt * 16 + (lane & 15);
            f1[i] = f2bf(w1[(oc * 32 + ic) * 9 + tap]);
        } else if (i < 27648) {               // conv2: IC=32 OC=64 NT=4 KS=1
            int v = i - 9216;
            int j = v & 7, lane = (v >> 3) & 63, nt = (v >> 9) & 3, tap = v >> 11;
            int ic = ((lane >> 4) * 8) + j, oc = nt * 16 + (lane & 15);
            f2[v] = f2bf(w2[(oc * 32 + ic) * 9 + tap]);
        } else if (i < 101376) {              // conv3: IC=64 OC=128 NT=8 KS=2
            int v = i - 27648;
            int j = v & 7, lane = (v >> 3) & 63, nt = (v >> 9) & 7, kk = v >> 12;
            int tap = kk >> 1, ks = kk & 1;
            int ic = ks * 32 + ((lane >> 4) * 8) + j, oc = nt * 16 + (lane & 15);
            f3[v] = f2bf(w3[(oc * 64 + ic) * 9 + tap]);
        }
    } else {
        int i = (blockIdx.x - 396) * 256 + threadIdx.x;
        if (i >= n * 4) return;
        int ci = i >> 2, q = i & 3;
        int b = coords[ci * 3 + 0], y = coords[ci * 3 + 1], x = coords[ci * 3 + 2];
        long base = ((long)((b * NH + y) * NW + x)) * NCIN + q * 8;
        const float4* src = (const float4*)(input + base);
        float4 v0 = src[0], v1 = src[1];
        union { short8 s8; unsigned short us[8]; } o;
        o.us[0] = f2bf(v0.x); o.us[1] = f2bf(v0.y); o.us[2] = f2bf(v0.z); o.us[3] = f2bf(v0.w);
        o.us[4] = f2bf(v1.x); o.us[5] = f2bf(v1.y); o.us[6] = f2bf(v1.z); o.us[7] = f2bf(v1.w);
        *(short8*)(inBf + base) = o.s8;
    }
}

// ---------------------------------------------------------------------------
// FUSED conv(3x3 s2 p1, MFMA) + maxpool3(s1 p1) + relu, bf16 out (R15).
// ---------------------------------------------------------------------------
template<int IC, int OC, int NTB, int TY, int TX, int IH, int IW, int OH, int OW>
__global__ __launch_bounds__(512) void convpool_mfma(
    const unsigned short* __restrict__ inPtr,  // NHWC bf16
    const unsigned short* __restrict__ wfrag,  // B-fragments bf16 (NT total tiles)
    const float* __restrict__ bias,
    unsigned short* __restrict__ outBf)        // pooled NHWC bf16
{
    constexpr int KS  = IC / 32;
    constexpr int NT  = OC / 16;               // total oc-tiles in wfrag
    constexpr int OCB = NTB * 16;              // oc per block
    constexpr int NOC = OC / OCB;
    constexpr int CY = TY + 2, CX = TX + 2;
    constexpr int NCELL  = CY * CX;
    constexpr int NSTRIP = (NCELL + 15) / 16;
    constexpr int CSS = OCB + 8;               // LDS cell stride (ushorts)
    constexpr int NTY = OH / TY, NTX = OW / TX;

    __shared__ __align__(16) unsigned short cs[NCELL * CSS];

    int bid = blockIdx.x;
    const int ocsel = bid % NOC; bid /= NOC;
    const int txi = bid % NTX;   bid /= NTX;
    const int tyi = bid % NTY;
    const int b   = bid / NTY;
    const int y0 = tyi * TY, x0 = txi * TX;

    const int t = threadIdx.x;
    const int wid = t >> 6, lane = t & 63, quad = lane >> 4, lm = lane & 15;

    short8 zero8;
    #pragma unroll
    for (int j = 0; j < 8; j++) zero8[j] = 0;

    // ---------------- phase 1: conv halo -> LDS bf16 ----------------
    for (int s = wid; s < NSTRIP; s += 8) {
        int idx = s * 16 + lm;
        if (idx > NCELL - 1) idx = NCELL - 1;          // clamp dummy lanes
        const int oy = y0 - 1 + idx / CX;
        const int ox = x0 - 1 + idx % CX;
        const int iy0 = oy * 2 - 1, ix0 = ox * 2 - 1;

        int cell[9]; bool okb[9];
        #pragma unroll
        for (int t9 = 0; t9 < 9; t9++) {
            const int iy = iy0 + t9 / 3;
            const int ix = ix0 + t9 % 3;
            const bool ok = (iy >= 0) && (iy < IH) && (ix >= 0) && (ix < IW);
            cell[t9] = ok ? ((b * IH + iy) * IW + ix) : 0;
            okb[t9] = ok;
        }

        f32x4 acc[NTB][2];
        #pragma unroll
        for (int nl = 0; nl < NTB; nl++)
            #pragma unroll
            for (int pp = 0; pp < 2; pp++)
                acc[nl][pp] = (f32x4){0.f, 0.f, 0.f, 0.f};

        #pragma unroll
        for (int ks = 0; ks < KS; ks++) {
            short8 av[9];
            #pragma unroll
            for (int t9 = 0; t9 < 9; t9++) {
                short8 v = *(const short8*)(inPtr + (long)cell[t9] * IC + ks * 32 + quad * 8);
                av[t9] = okb[t9] ? v : zero8;
            }
            #pragma unroll
            for (int nl = 0; nl < NTB; nl++) {
                const int nt = ocsel * NTB + nl;
                #pragma unroll
                for (int t9 = 0; t9 < 9; t9++) {
                    short8 bf = *(const short8*)(wfrag + (((t9 * KS + ks) * NT + nt) * 64 + lane) * 8);
                    if (t9 & 1) acc[nl][1] = __builtin_amdgcn_mfma_f32_16x16x32_bf16(av[t9], bf, acc[nl][1], 0, 0, 0);
                    else        acc[nl][0] = __builtin_amdgcn_mfma_f32_16x16x32_bf16(av[t9], bf, acc[nl][0], 0, 0, 0);
                }
            }
        }

        // D-store to LDS: lane holds rows quad*4+reg, col lm
        #pragma unroll
        for (int nl = 0; nl < NTB; nl++) {
            const float bv = bias[(ocsel * NTB + nl) * 16 + lm];
            #pragma unroll
            for (int reg = 0; reg < 4; reg++) {
                const int ci = s * 16 + quad * 4 + reg;
                if (ci < NCELL)
                    cs[ci * CSS + nl * 16 + lm] = f2bf(acc[nl][0][reg] + acc[nl][1][reg] + bv);
            }
        }
    }
    __syncthreads();

    // ---------------- phase 2: pool 3x3 s1 p1 + relu -> global bf16 ----------------
    constexpr int NTASK = TY * TX * (OCB / 8);
    for (int u = t; u < NTASK; u += 512) {
        const int c8 = u & (OCB / 8 - 1);
        const int px = (u / (OCB / 8)) % TX;
        const int py = u / ((OCB / 8) * TX);
        const int gy = y0 + py, gx = x0 + px;

        float m[8];
        #pragma unroll
        for (int e = 0; e < 8; e++) m[e] = 0.f;        // relu floor

        #pragma unroll
        for (int dy = -1; dy <= 1; dy++) {
            const int yy = gy + dy;
            if (yy < 0 || yy >= OH) continue;
            #pragma unroll
            for (int dx = -1; dx <= 1; dx++) {
                const int xx = gx + dx;
                if (xx < 0 || xx >= OW) continue;
                const int ci = (py + dy + 1) * CX + (px + dx + 1);
                short8 v = *(const short8*)(&cs[ci * CSS + c8 * 8]);
                #pragma unroll
                for (int e = 0; e < 8; e++)
                    m[e] = fmaxf(m[e], bf2f((unsigned short)v[e]));
            }
        }
        union { short8 s8; unsigned short us[8]; } o;
        #pragma unroll
        for (int e = 0; e < 8; e++) o.us[e] = fhi(m[e]);   // exact repack
        *(short8*)(outBf + ((long)((b * OH + gy) * OW + gx)) * OC + ocsel * OCB + c8 * 8) = o.s8;
    }
}

// ---------------------------------------------------------------------------
// Implicit-GEMM conv (unfused; used for conv3 only). Unchanged.
// ---------------------------------------------------------------------------
template<int IC, int OC, int NL, int IH, int IW, int OH, int OW>
__global__ __launch_bounds__(256) void conv_mfma(
    const unsigned short* __restrict__ inPtr,
    const unsigned short* __restrict__ wfrag,
    const float* __restrict__ bias,
    float* __restrict__ out)
{
    constexpr int KS = IC / 32;
    constexpr int NT = OC / 16;
    constexpr int NG = NT / NL;
    constexpr int NSTRIPS = NB * OH * OW / 16;

    const int wid  = (blockIdx.x * 256 + threadIdx.x) >> 6;
    const int lane = threadIdx.x & 63;
    const int ntb  = (wid % NG) * NL;
    const int s    = wid / NG;
    if (s >= NSTRIPS) return;
    const int quad = lane >> 4;
    const int lm   = lane & 15;

    const int p0 = s * 16;
    const int posA = p0 + lm;
    const int b  = posA / (OH * OW);
    const int rr = posA % (OH * OW);
    const int oy = rr / OW, ox = rr % OW;
    const int iy0 = oy * 2 - 1, ix0 = ox * 2 - 1;

    int cell[9];
    bool okb[9];
    #pragma unroll
    for (int t9 = 0; t9 < 9; t9++) {
        const int iy = iy0 + t9 / 3;
        const int ix = ix0 + t9 % 3;
        const bool ok = (iy >= 0) && (iy < IH) && (ix >= 0) && (ix < IW);
        cell[t9] = ok ? ((b * IH + iy) * IW + ix) : 0;
        okb[t9] = ok;
    }

    short8 zero8;
    #pragma unroll
    for (int j = 0; j < 8; j++) zero8[j] = 0;

    f32x4 acc[NL][2];
    #pragma unroll
    for (int nl = 0; nl < NL; nl++)
        #pragma unroll
        for (int pp = 0; pp < 2; pp++)
            acc[nl][pp] = (f32x4){0.f, 0.f, 0.f, 0.f};

    #pragma unroll 1
    for (int ks = 0; ks < KS; ks++) {
        short8 av[9];
        #pragma unroll
        for (int t9 = 0; t9 < 9; t9++) {
            short8 v = *(const short8*)(inPtr + (long)cell[t9] * IC + ks * 32 + quad * 8);
            av[t9] = okb[t9] ? v : zero8;
        }
        #pragma unroll
        for (int nl = 0; nl < NL; nl++) {
            #pragma unroll
            for (int t9 = 0; t9 < 9; t9++) {
                short8 bf = *(const short8*)(wfrag + (((t9 * KS + ks) * NT + ntb + nl) * 64 + lane) * 8);
                if (t9 & 1) acc[nl][1] = __builtin_amdgcn_mfma_f32_16x16x32_bf16(av[t9], bf, acc[nl][1], 0, 0, 0);
                else        acc[nl][0] = __builtin_amdgcn_mfma_f32_16x16x32_bf16(av[t9], bf, acc[nl][0], 0, 0, 0);
            }
        }
    }

    const long rowBase = (long)p0 + quad * 4;
    #pragma unroll
    for (int nl = 0; nl < NL; nl++) {
        const int oc = (ntb + nl) * 16 + lm;
        const float bv = bias[oc];
        #pragma unroll
        for (int reg = 0; reg < 4; reg++)
            out[(rowBase + reg) * OC + oc] = acc[nl][0][reg] + acc[nl][1][reg] + bv;
    }
}

// ---------------------------------------------------------------------------
// FUSED maxpool3+relu (fp32 exact) + transpose for the FC (unchanged).
// ---------------------------------------------------------------------------
__global__ __launch_bounds__(256) void pool_transpose(const float* __restrict__ conv3o,
                                                      float* __restrict__ xT) {
    __shared__ float tile_s[8 * 16 * 17];     // [c_l][pos_l][b(pad 17)]
    const int pt = blockIdx.x % 30;
    const int ct = blockIdx.x / 30;           // 0..15
    const int pos0 = pt * 16, c0 = ct * 8;
    const int t = threadIdx.x;
    {
        const int b = t >> 4, pl = t & 15;
        const int pos = pos0 + pl;
        const int py = pos / 40, px = pos % 40;
        float4 m0 = make_float4(0.f, 0.f, 0.f, 0.f);   // relu floor
        float4 m1 = make_float4(0.f, 0.f, 0.f, 0.f);
        #pragma unroll
        for (int dy = -1; dy <= 1; dy++) {
            const int yy = py + dy;
            if (yy < 0 || yy >= 12) continue;
            #pragma unroll
            for (int dx = -1; dx <= 1; dx++) {
                const int xx = px + dx;
                if (xx < 0 || xx >= 40) continue;
                const float4* src = (const float4*)(conv3o + ((long)((b * 12 + yy) * 40 + xx)) * 128 + c0);
                float4 v0 = src[0], v1 = src[1];
                m0.x = fmaxf(m0.x, v0.x); m0.y = fmaxf(m0.y, v0.y);
                m0.z = fmaxf(m0.z, v0.z); m0.w = fmaxf(m0.w, v0.w);
                m1.x = fmaxf(m1.x, v1.x); m1.y = fmaxf(m1.y, v1.y);
                m1.z = fmaxf(m1.z, v1.z); m1.w = fmaxf(m1.w, v1.w);
            }
        }
        tile_s[(0 * 16 + pl) * 17 + b] = m0.x;
        tile_s[(1 * 16 + pl) * 17 + b] = m0.y;
        tile_s[(2 * 16 + pl) * 17 + b] = m0.z;
        tile_s[(3 * 16 + pl) * 17 + b] = m0.w;
        tile_s[(4 * 16 + pl) * 17 + b] = m1.x;
        tile_s[(5 * 16 + pl) * 17 + b] = m1.y;
        tile_s[(6 * 16 + pl) * 17 + b] = m1.z;
        tile_s[(7 * 16 + pl) * 17 + b] = m1.w;
    }
    __syncthreads();
    {
        const int w = t >> 6, l = t & 63;
        const int pl2 = l >> 2, b4 = l & 3;
        #pragma unroll
        for (int i = 0; i < 2; i++) {
            int cl = w + 4 * i;
            const float* ls = &tile_s[(cl * 16 + pl2) * 17 + 4 * b4];
            float4 v = make_float4(ls[0], ls[1], ls[2], ls[3]);
            *(float4*)(xT + ((long)(c0 + cl) * 480 + pos0 + pl2) * 16 + 4 * b4) = v;
        }
    }
}

// ---------------------------------------------------------------------------
// FC main v10 (R18): async global_load_lds weight staging.
// Three rounds of evidence (v3 VGPR=84, v8 VGPR=44, v9 PIN4-null) prove the
// compiler sinks/reloads register-preloaded weights no matter the source
// shape -> ~1-2 loads in flight -> ~1.2 TB/s demand rate, fc ~37 us.
// global_load_lds has NO destination VGPR: it cannot be sunk, split, or
// reloaded. 4 phases of 32 k, double-buffered 32 KB LDS weight chunks;
// per phase each wave issues 4 fire-and-forget 1 KB DMAs -> 64 KB/CU in
// flight >> the ~22 KB BW*latency product: stream saturates by construction.
// Bank conflicts (128 B oc-rows = 16-way) fixed per rule #21: LINEAR DMA
// dest + inverse-XOR'd global SOURCE + XOR on READ (g' = g ^ (oc&7)) ->
// minimum 8 words/bank. Compute mapping, accumulation order, partial layout
// identical to the passing v7 (numerics unchanged). LDS 74 KB -> 2 blk/CU.
// ---------------------------------------------------------------------------
__global__ __launch_bounds__(512, 4) void fc_main(const float* __restrict__ xT,
                                                  const float* __restrict__ fw,
                                                  float* __restrict__ partial)
{
    __shared__ float wbuf[2][8192];            // 2 x 32 KB: [oc 0..255][8 granules of 4 floats]
    __shared__ float x_lds[128 * 20];          // 10 KB, row stride 20 floats
    const int kc   = blockIdx.x;
    const int t    = threadIdx.x;
    const int q    = t >> 2;                   // oc group 0..127 (owns q, q+128)
    const int ksub = t & 3;
    const int k0   = kc * FC_KB;

    // ---- stage helper: phase pp -> wbuf[pp&1]; 4 DMAs/thread-slot ----
    // chunk c (16 B): row r = c>>3 (oc), stored granule g' = c&7,
    // source granule g = g' ^ (r&7)  [inverse swizzle on the SOURCE]
    #define FC_STAGE(pp)                                                       \
        _Pragma("unroll")                                                      \
        for (int i = 0; i < 4; i++) {                                          \
            const int c = i * 512 + t;                                         \
            const int r = c >> 3;                                              \
            const int g = (c & 7) ^ (r & 7);                                   \
            gload_lds16(fw + (long)r * FC_K + k0 + (pp) * 32 + g * 4,          \
                        &wbuf[(pp) & 1][c * 4]);                               \
        }

    // prologue: stage phase 0 + x tile
    FC_STAGE(0);
    {
        const int kr = t >> 2, b4 = t & 3;
        *(float4*)(&x_lds[kr * 20 + b4 * 4]) =
            *(const float4*)(xT + ((long)(k0 + kr)) * 16 + b4 * 4);
    }
    asm volatile("s_waitcnt vmcnt(0)" ::: "memory");
    __syncthreads();

    float acc[2][16];
    #pragma unroll
    for (int s = 0; s < 2; s++)
        #pragma unroll
        for (int b = 0; b < 16; b++) acc[s][b] = 0.f;

    const int h = q & 7;                       // (q&7) == ((q+128)&7)

    #pragma unroll
    for (int p = 0; p < 4; p++) {
        if (p < 3) { FC_STAGE(p + 1); }        // fire-and-forget next chunk

        const float* wb = wbuf[p & 1];
        #pragma unroll
        for (int j = 0; j < 2; j++) {
            const int gp = (ksub + 4 * j) ^ h;             // swizzled granule
            const f32x4 w0 = *(const f32x4*)(wb + q * 32 + gp * 4);
            const f32x4 w1 = *(const f32x4*)(wb + (q + 128) * 32 + gp * 4);
            #pragma unroll
            for (int e = 0; e < 4; e++) {
                const int row = p * 32 + j * 16 + ksub * 4 + e;
                const float* xr = &x_lds[row * 20];
                f32x4 xv[4];
                #pragma unroll
                for (int b4 = 0; b4 < 4; b4++)
                    xv[b4] = *(const f32x4*)(xr + 4 * b4);
                #pragma unroll
                for (int b4 = 0; b4 < 4; b4++)
                    #pragma unroll
                    for (int el = 0; el < 4; el++) {
                        acc[0][b4 * 4 + el] = fmaf(w0[e], xv[b4][el], acc[0][b4 * 4 + el]);
                        acc[1][b4 * 4 + el] = fmaf(w1[e], xv[b4][el], acc[1][b4 * 4 + el]);
                    }
            }
        }
        asm volatile("s_waitcnt vmcnt(0)" ::: "memory");   // next chunk landed
        __syncthreads();
    }
    #undef FC_STAGE

    #pragma unroll
    for (int s = 0; s < 2; s++)
        #pragma unroll
        for (int b = 0; b < 16; b++) {
            float v = acc[s][b];
            v += __shfl_xor(v, 1);
            v += __shfl_xor(v, 2);
            acc[s][b] = v;
        }

    if (ksub == 0) {
        #pragma unroll
        for (int s = 0; s < 2; s++) {
            const int oc = q + 128 * s;
            float4* pp = (float4*)(partial + ((long)kc * 256 + oc) * 16);
            pp[0] = make_float4(acc[s][0],  acc[s][1],  acc[s][2],  acc[s][3]);
            pp[1] = make_float4(acc[s][4],  acc[s][5],  acc[s][6],  acc[s][7]);
            pp[2] = make_float4(acc[s][8],  acc[s][9],  acc[s][10], acc[s][11]);
            pp[3] = make_float4(acc[s][12], acc[s][13], acc[s][14], acc[s][15]);
        }
    }
}

__global__ __launch_bounds__(256) void fc_reduce(const float* __restrict__ partial,
                                                 const float* __restrict__ fcb,
                                                 float* __restrict__ out)
{
    __shared__ float red[16][17];
    const int oc = blockIdx.x;
    const int ol = threadIdx.x & 15;
    const int st = threadIdx.x >> 4;
    float s = 0.f;
    #pragma unroll 5
    for (int j = 0; j < 30; j++)
        s += partial[(long)(st + 16 * j) * 4096 + oc * 16 + ol];
    red[st][ol] = s;
    __syncthreads();
    if (threadIdx.x < 16) {
        float tot = fcb[oc];
        #pragma unroll
        for (int k = 0; k < 16; k++) tot += red[k][threadIdx.x];
        out[threadIdx.x * 256 + oc] = fmaxf(tot, 0.f);
    }
}

// ---------------------------------------------------------------------------
extern "C" void kernel_launch(void* const* d_in, const int* in_sizes, int n_in,
                              void* d_out, int out_size, void* d_ws, size_t ws_size,
                              hipStream_t stream) {
    const float* input  = (const float*)d_in[0];
    const int*   coords = (const int*)d_in[1];
    const float* w1 = (const float*)d_in[2];
    const float* b1 = (const float*)d_in[3];
    const float* w2 = (const float*)d_in[4];
    const float* b2 = (const float*)d_in[5];
    const float* w3 = (const float*)d_in[6];
    const float* b3 = (const float*)d_in[7];
    const float* fcw = (const float*)d_in[8];
    const float* fcb = (const float*)d_in[9];
    float* outp = (float*)d_out;

    const int n_active = in_sizes[1] / 3;

    // ---- workspace layout (R6/R8) ----
    char* ws = (char*)d_ws;
    unsigned short* wf1 = (unsigned short*)ws;                    // 18,432 B
    unsigned short* wf2 = wf1 + 9216;                             // 36,864 B
    unsigned short* wf3 = wf2 + 18432;                            // 147,456 B
    unsigned short* inBf    = (unsigned short*)(ws + 204800);     // 31,457,280 B
    unsigned short* pool1bf = (unsigned short*)(ws + 31662080);   //  7,864,320 B
    unsigned short* pool2bf = (unsigned short*)(ws + 39526400);   //  3,932,160 B
    float*          conv3o  = (float*)(ws + 43458560);            //  3,932,160 B
    float*          xT      = (float*)(ws + 47390720);            //  3,932,160 B
    float*          partial = (float*)(ws + 51322880);            //  7,864,320 B

    // zero dense bf16 input, then fused wfrag-prep + scatter-cast.
    hipMemsetAsync(inBf, 0, 31457280, stream);
    const int scatterBlocks = (n_active * 4 + 255) / 256;
    setup_all<<<396 + scatterBlocks, 256, 0, stream>>>(w1, w2, w3, wf1, wf2, wf3,
                                                       coords, input, inBf, n_active);

    // conv1+pool1 fused: (16,96,320,32)->(16,48,160,32) bf16
    convpool_mfma<32, 32, 2, 16, 16, 96, 320, 48, 160>
        <<<480, 512, 0, stream>>>(inBf, wf1, b1, pool1bf);

    // conv2+pool2 fused: (16,48,160,32)->(16,24,80,64) bf16
    convpool_mfma<32, 64, 2, 8, 16, 48, 160, 24, 80>
        <<<480, 512, 0, stream>>>(pool1bf, wf2, b2, pool2bf);

    // conv3 (unfused, fp32 out): (16,24,80,64)->(16,12,40,128); NL=1
    conv_mfma<64, 128, 1, 24, 80, 12, 40>
        <<<960, 256, 0, stream>>>(pool2bf, wf3, b3, conv3o);

    // pool3+transpose fused (fp32 exact) -> xT
    pool_transpose<<<480, 256, 0, stream>>>(conv3o, xT);

    // FC (async-staged weights)
    fc_main<<<FC_NKC, 512, 0, stream>>>(xT, fcw, partial);
    fc_reduce<<<256, 256, 0, stream>>>(partial, fcb, outp);
}

// Round 10
// 230.888 us; speedup vs baseline: 1.1054x; 1.1054x over previous
//
#include <hip/hip_runtime.h>

// Problem constants
#define NB 16
#define NH 96
#define NW 320
#define NCIN 32

#define FC_K 61440
#define FC_KB 128          // k per block
#define FC_NKC 480         // 61440/128 chunks

typedef __attribute__((ext_vector_type(8))) short short8;     // 8 bf16 (4 VGPRs)
typedef __attribute__((ext_vector_type(4))) float f32x4;

__device__ inline unsigned short f2bf(float f) {
    union { float f; unsigned int u; } v; v.f = f;
    unsigned int r = v.u + 0x7FFF + ((v.u >> 16) & 1);   // RNE
    return (unsigned short)(r >> 16);
}
__device__ inline float bf2f(unsigned short s) {
    union { unsigned int u; float f; } v; v.u = ((unsigned int)s) << 16; return v.f;
}
__device__ inline unsigned short fhi(float f) {        // exact for bf16-valued floats
    union { float f; unsigned int u; } v; v.f = f; return (unsigned short)(v.u >> 16);
}

// ---------------------------------------------------------------------------
// Fused setup kernel (unchanged): wfrag prep + scatter-cast of active cells.
// ---------------------------------------------------------------------------
__global__ __launch_bounds__(256) void setup_all(const float* __restrict__ w1,
                                                 const float* __restrict__ w2,
                                                 const float* __restrict__ w3,
                                                 unsigned short* __restrict__ f1,
                                                 unsigned short* __restrict__ f2,
                                                 unsigned short* __restrict__ f3,
                                                 const int* __restrict__ coords,
                                                 const float* __restrict__ input,
                                                 unsigned short* __restrict__ inBf,
                                                 int n) {
    if (blockIdx.x < 396) {
        int i = blockIdx.x * 256 + threadIdx.x;
        if (i < 9216) {                       // conv1: IC=32 OC=32 NT=2 KS=1
            int j = i & 7, lane = (i >> 3) & 63, nt = (i >> 9) & 1, tap = i >> 10;
            int ic = ((lane >> 4) * 8) + j, oc = nt * 16 + (lane & 15);
            f1[i] = f2bf(w1[(oc * 32 + ic) * 9 + tap]);
        } else if (i < 27648) {               // conv2: IC=32 OC=64 NT=4 KS=1
            int v = i - 9216;
            int j = v & 7, lane = (v >> 3) & 63, nt = (v >> 9) & 3, tap = v >> 11;
            int ic = ((lane >> 4) * 8) + j, oc = nt * 16 + (lane & 15);
            f2[v] = f2bf(w2[(oc * 32 + ic) * 9 + tap]);
        } else if (i < 101376) {              // conv3: IC=64 OC=128 NT=8 KS=2
            int v = i - 27648;
            int j = v & 7, lane = (v >> 3) & 63, nt = (v >> 9) & 7, kk = v >> 12;
            int tap = kk >> 1, ks = kk & 1;
            int ic = ks * 32 + ((lane >> 4) * 8) + j, oc = nt * 16 + (lane & 15);
            f3[v] = f2bf(w3[(oc * 64 + ic) * 9 + tap]);
        }
    } else {
        int i = (blockIdx.x - 396) * 256 + threadIdx.x;
        if (i >= n * 4) return;
        int ci = i >> 2, q = i & 3;
        int b = coords[ci * 3 + 0], y = coords[ci * 3 + 1], x = coords[ci * 3 + 2];
        long base = ((long)((b * NH + y) * NW + x)) * NCIN + q * 8;
        const float4* src = (const float4*)(input + base);
        float4 v0 = src[0], v1 = src[1];
        union { short8 s8; unsigned short us[8]; } o;
        o.us[0] = f2bf(v0.x); o.us[1] = f2bf(v0.y); o.us[2] = f2bf(v0.z); o.us[3] = f2bf(v0.w);
        o.us[4] = f2bf(v1.x); o.us[5] = f2bf(v1.y); o.us[6] = f2bf(v1.z); o.us[7] = f2bf(v1.w);
        *(short8*)(inBf + base) = o.s8;
    }
}

// ---------------------------------------------------------------------------
// FUSED conv(3x3 s2 p1, MFMA) + maxpool3(s1 p1) + relu, bf16 out.
// R19 retile: 256-thread blocks, tiles chosen so strips divide waves EXACTLY
// and grid >= 3 blocks/CU. Old shape (480 blocks x 512 thr = 1.875/CU,
// 21 strips / 8 waves ragged) left half the CUs idle in the tail; the conv
// stage (~140us incl. setup/gaps by R8 subtraction) is the unprofiled bulk.
// conv1: 8x16 tile -> 960 blocks (3.75/CU), 12 strips / 4 waves = 3 exact.
// conv2: 8x10 tile -> 768 blocks (3.0/CU),   8 strips / 4 waves = 2 exact.
// ---------------------------------------------------------------------------
template<int IC, int OC, int NTB, int TY, int TX, int IH, int IW, int OH, int OW, int TPB>
__global__ __launch_bounds__(TPB) void convpool_mfma(
    const unsigned short* __restrict__ inPtr,  // NHWC bf16
    const unsigned short* __restrict__ wfrag,  // B-fragments bf16 (NT total tiles)
    const float* __restrict__ bias,
    unsigned short* __restrict__ outBf)        // pooled NHWC bf16
{
    constexpr int KS  = IC / 32;
    constexpr int NT  = OC / 16;               // total oc-tiles in wfrag
    constexpr int OCB = NTB * 16;              // oc per block
    constexpr int NOC = OC / OCB;
    constexpr int CY = TY + 2, CX = TX + 2;
    constexpr int NCELL  = CY * CX;
    constexpr int NSTRIP = (NCELL + 15) / 16;
    constexpr int CSS = OCB + 8;               // LDS cell stride (ushorts)
    constexpr int NTY = OH / TY, NTX = OW / TX;
    constexpr int NWAVE = TPB / 64;

    __shared__ __align__(16) unsigned short cs[NCELL * CSS];

    int bid = blockIdx.x;
    const int ocsel = bid % NOC; bid /= NOC;
    const int txi = bid % NTX;   bid /= NTX;
    const int tyi = bid % NTY;
    const int b   = bid / NTY;
    const int y0 = tyi * TY, x0 = txi * TX;

    const int t = threadIdx.x;
    const int wid = t >> 6, lane = t & 63, quad = lane >> 4, lm = lane & 15;

    short8 zero8;
    #pragma unroll
    for (int j = 0; j < 8; j++) zero8[j] = 0;

    // ---------------- phase 1: conv halo -> LDS bf16 ----------------
    for (int s = wid; s < NSTRIP; s += NWAVE) {
        int idx = s * 16 + lm;
        if (idx > NCELL - 1) idx = NCELL - 1;          // clamp dummy lanes
        const int oy = y0 - 1 + idx / CX;
        const int ox = x0 - 1 + idx % CX;
        const int iy0 = oy * 2 - 1, ix0 = ox * 2 - 1;

        int cell[9]; bool okb[9];
        #pragma unroll
        for (int t9 = 0; t9 < 9; t9++) {
            const int iy = iy0 + t9 / 3;
            const int ix = ix0 + t9 % 3;
            const bool ok = (iy >= 0) && (iy < IH) && (ix >= 0) && (ix < IW);
            cell[t9] = ok ? ((b * IH + iy) * IW + ix) : 0;
            okb[t9] = ok;
        }

        f32x4 acc[NTB][2];
        #pragma unroll
        for (int nl = 0; nl < NTB; nl++)
            #pragma unroll
            for (int pp = 0; pp < 2; pp++)
                acc[nl][pp] = (f32x4){0.f, 0.f, 0.f, 0.f};

        #pragma unroll
        for (int ks = 0; ks < KS; ks++) {
            short8 av[9];
            #pragma unroll
            for (int t9 = 0; t9 < 9; t9++) {
                short8 v = *(const short8*)(inPtr + (long)cell[t9] * IC + ks * 32 + quad * 8);
                av[t9] = okb[t9] ? v : zero8;
            }
            #pragma unroll
            for (int nl = 0; nl < NTB; nl++) {
                const int nt = ocsel * NTB + nl;
                #pragma unroll
                for (int t9 = 0; t9 < 9; t9++) {
                    short8 bf = *(const short8*)(wfrag + (((t9 * KS + ks) * NT + nt) * 64 + lane) * 8);
                    if (t9 & 1) acc[nl][1] = __builtin_amdgcn_mfma_f32_16x16x32_bf16(av[t9], bf, acc[nl][1], 0, 0, 0);
                    else        acc[nl][0] = __builtin_amdgcn_mfma_f32_16x16x32_bf16(av[t9], bf, acc[nl][0], 0, 0, 0);
                }
            }
        }

        // D-store to LDS: lane holds rows quad*4+reg, col lm
        #pragma unroll
        for (int nl = 0; nl < NTB; nl++) {
            const float bv = bias[(ocsel * NTB + nl) * 16 + lm];
            #pragma unroll
            for (int reg = 0; reg < 4; reg++) {
                const int ci = s * 16 + quad * 4 + reg;
                if (ci < NCELL)
                    cs[ci * CSS + nl * 16 + lm] = f2bf(acc[nl][0][reg] + acc[nl][1][reg] + bv);
            }
        }
    }
    __syncthreads();

    // ---------------- phase 2: pool 3x3 s1 p1 + relu -> global bf16 ----------------
    constexpr int NTASK = TY * TX * (OCB / 8);
    for (int u = t; u < NTASK; u += TPB) {
        const int c8 = u & (OCB / 8 - 1);
        const int px = (u / (OCB / 8)) % TX;
        const int py = u / ((OCB / 8) * TX);
        const int gy = y0 + py, gx = x0 + px;

        float m[8];
        #pragma unroll
        for (int e = 0; e < 8; e++) m[e] = 0.f;        // relu floor

        #pragma unroll
        for (int dy = -1; dy <= 1; dy++) {
            const int yy = gy + dy;
            if (yy < 0 || yy >= OH) continue;
            #pragma unroll
            for (int dx = -1; dx <= 1; dx++) {
                const int xx = gx + dx;
                if (xx < 0 || xx >= OW) continue;
                const int ci = (py + dy + 1) * CX + (px + dx + 1);
                short8 v = *(const short8*)(&cs[ci * CSS + c8 * 8]);
                #pragma unroll
                for (int e = 0; e < 8; e++)
                    m[e] = fmaxf(m[e], bf2f((unsigned short)v[e]));
            }
        }
        union { short8 s8; unsigned short us[8]; } o;
        #pragma unroll
        for (int e = 0; e < 8; e++) o.us[e] = fhi(m[e]);   // exact repack
        *(short8*)(outBf + ((long)((b * OH + gy) * OW + gx)) * OC + ocsel * OCB + c8 * 8) = o.s8;
    }
}

// ---------------------------------------------------------------------------
// Implicit-GEMM conv (unfused; used for conv3 only). Unchanged.
// ---------------------------------------------------------------------------
template<int IC, int OC, int NL, int IH, int IW, int OH, int OW>
__global__ __launch_bounds__(256) void conv_mfma(
    const unsigned short* __restrict__ inPtr,
    const unsigned short* __restrict__ wfrag,
    const float* __restrict__ bias,
    float* __restrict__ out)
{
    constexpr int KS = IC / 32;
    constexpr int NT = OC / 16;
    constexpr int NG = NT / NL;
    constexpr int NSTRIPS = NB * OH * OW / 16;

    const int wid  = (blockIdx.x * 256 + threadIdx.x) >> 6;
    const int lane = threadIdx.x & 63;
    const int ntb  = (wid % NG) * NL;
    const int s    = wid / NG;
    if (s >= NSTRIPS) return;
    const int quad = lane >> 4;
    const int lm   = lane & 15;

    const int p0 = s * 16;
    const int posA = p0 + lm;
    const int b  = posA / (OH * OW);
    const int rr = posA % (OH * OW);
    const int oy = rr / OW, ox = rr % OW;
    const int iy0 = oy * 2 - 1, ix0 = ox * 2 - 1;

    int cell[9];
    bool okb[9];
    #pragma unroll
    for (int t9 = 0; t9 < 9; t9++) {
        const int iy = iy0 + t9 / 3;
        const int ix = ix0 + t9 % 3;
        const bool ok = (iy >= 0) && (iy < IH) && (ix >= 0) && (ix < IW);
        cell[t9] = ok ? ((b * IH + iy) * IW + ix) : 0;
        okb[t9] = ok;
    }

    short8 zero8;
    #pragma unroll
    for (int j = 0; j < 8; j++) zero8[j] = 0;

    f32x4 acc[NL][2];
    #pragma unroll
    for (int nl = 0; nl < NL; nl++)
        #pragma unroll
        for (int pp = 0; pp < 2; pp++)
            acc[nl][pp] = (f32x4){0.f, 0.f, 0.f, 0.f};

    #pragma unroll 1
    for (int ks = 0; ks < KS; ks++) {
        short8 av[9];
        #pragma unroll
        for (int t9 = 0; t9 < 9; t9++) {
            short8 v = *(const short8*)(inPtr + (long)cell[t9] * IC + ks * 32 + quad * 8);
            av[t9] = okb[t9] ? v : zero8;
        }
        #pragma unroll
        for (int nl = 0; nl < NL; nl++) {
            #pragma unroll
            for (int t9 = 0; t9 < 9; t9++) {
                short8 bf = *(const short8*)(wfrag + (((t9 * KS + ks) * NT + ntb + nl) * 64 + lane) * 8);
                if (t9 & 1) acc[nl][1] = __builtin_amdgcn_mfma_f32_16x16x32_bf16(av[t9], bf, acc[nl][1], 0, 0, 0);
                else        acc[nl][0] = __builtin_amdgcn_mfma_f32_16x16x32_bf16(av[t9], bf, acc[nl][0], 0, 0, 0);
            }
        }
    }

    const long rowBase = (long)p0 + quad * 4;
    #pragma unroll
    for (int nl = 0; nl < NL; nl++) {
        const int oc = (ntb + nl) * 16 + lm;
        const float bv = bias[oc];
        #pragma unroll
        for (int reg = 0; reg < 4; reg++)
            out[(rowBase + reg) * OC + oc] = acc[nl][0][reg] + acc[nl][1][reg] + bv;
    }
}

// ---------------------------------------------------------------------------
// FUSED maxpool3+relu (fp32 exact) + transpose for the FC (unchanged).
// ---------------------------------------------------------------------------
__global__ __launch_bounds__(256) void pool_transpose(const float* __restrict__ conv3o,
                                                      float* __restrict__ xT) {
    __shared__ float tile_s[8 * 16 * 17];     // [c_l][pos_l][b(pad 17)]
    const int pt = blockIdx.x % 30;
    const int ct = blockIdx.x / 30;           // 0..15
    const int pos0 = pt * 16, c0 = ct * 8;
    const int t = threadIdx.x;
    {
        const int b = t >> 4, pl = t & 15;
        const int pos = pos0 + pl;
        const int py = pos / 40, px = pos % 40;
        float4 m0 = make_float4(0.f, 0.f, 0.f, 0.f);   // relu floor
        float4 m1 = make_float4(0.f, 0.f, 0.f, 0.f);
        #pragma unroll
        for (int dy = -1; dy <= 1; dy++) {
            const int yy = py + dy;
            if (yy < 0 || yy >= 12) continue;
            #pragma unroll
            for (int dx = -1; dx <= 1; dx++) {
                const int xx = px + dx;
                if (xx < 0 || xx >= 40) continue;
                const float4* src = (const float4*)(conv3o + ((long)((b * 12 + yy) * 40 + xx)) * 128 + c0);
                float4 v0 = src[0], v1 = src[1];
                m0.x = fmaxf(m0.x, v0.x); m0.y = fmaxf(m0.y, v0.y);
                m0.z = fmaxf(m0.z, v0.z); m0.w = fmaxf(m0.w, v0.w);
                m1.x = fmaxf(m1.x, v1.x); m1.y = fmaxf(m1.y, v1.y);
                m1.z = fmaxf(m1.z, v1.z); m1.w = fmaxf(m1.w, v1.w);
            }
        }
        tile_s[(0 * 16 + pl) * 17 + b] = m0.x;
        tile_s[(1 * 16 + pl) * 17 + b] = m0.y;
        tile_s[(2 * 16 + pl) * 17 + b] = m0.z;
        tile_s[(3 * 16 + pl) * 17 + b] = m0.w;
        tile_s[(4 * 16 + pl) * 17 + b] = m1.x;
        tile_s[(5 * 16 + pl) * 17 + b] = m1.y;
        tile_s[(6 * 16 + pl) * 17 + b] = m1.z;
        tile_s[(7 * 16 + pl) * 17 + b] = m1.w;
    }
    __syncthreads();
    {
        const int w = t >> 6, l = t & 63;
        const int pl2 = l >> 2, b4 = l & 3;
        #pragma unroll
        for (int i = 0; i < 2; i++) {
            int cl = w + 4 * i;
            const float* ls = &tile_s[(cl * 16 + pl2) * 17 + 4 * b4];
            float4 v = make_float4(ls[0], ls[1], ls[2], ls[3]);
            *(float4*)(xT + ((long)(c0 + cl) * 480 + pos0 + pl2) * 16 + 4 * b4) = v;
        }
    }
}

// ---------------------------------------------------------------------------
// FC main v9 (R17/R8 best, restored): register preload + PIN4 anti-sink.
// v10's async global_load_lds regressed (60us, WRITE_SIZE=73MB anomaly --
// per-lane LDS dest violates the wave-uniform-dest rule, legalization
// serialized the staging). v9/v7 = 37us is the best measured FC; FC micro-
// opts are parked -- the conv stage holds ~3x more unexplained time.
// ---------------------------------------------------------------------------
#define PIN4(v_) asm volatile("" :: "v"((float)(v_)[0]), "v"((float)(v_)[1]), \
                                     "v"((float)(v_)[2]), "v"((float)(v_)[3]))

__global__ __launch_bounds__(512, 4) void fc_main(const float* __restrict__ xT,
                                                  const float* __restrict__ fw,
                                                  float* __restrict__ partial)
{
    __shared__ float x_lds[128 * 20];
    const int kc   = blockIdx.x;
    const int t    = threadIdx.x;
    const int q    = t >> 2;
    const int ksub = t & 3;
    const int k0   = kc * FC_KB;

    // ---- issue ALL 16 weight loads first (independent of LDS stage) ----
    const float* wbase = fw + (long)q * FC_K + k0 + ksub * 4;
    f32x4 w[2][8];
    #pragma unroll
    for (int s = 0; s < 2; s++) {
        const float* wr = wbase + (long)s * (128 * FC_K);
        #pragma unroll
        for (int j = 0; j < 8; j++)
            w[s][j] = *(const f32x4*)(wr + j * 16);
    }

    // ---- stage x[128][16] into LDS (overlaps weight-load latency) ----
    {
        const int kr = t >> 2, b4 = t & 3;
        *(float4*)(&x_lds[kr * 20 + b4 * 4]) =
            *(const float4*)(xT + ((long)(k0 + kr)) * 16 + b4 * 4);
    }

    // ---- anti-sink fence: all 16 loads must be materialized HERE ----
    #pragma unroll
    for (int s = 0; s < 2; s++)
        #pragma unroll
        for (int j = 0; j < 8; j++)
            PIN4(w[s][j]);

    __syncthreads();

    float acc[2][16];
    #pragma unroll
    for (int s = 0; s < 2; s++)
        #pragma unroll
        for (int b = 0; b < 16; b++) acc[s][b] = 0.f;

    #pragma unroll
    for (int j = 0; j < 8; j++) {
        #pragma unroll
        for (int e = 0; e < 4; e++) {
            const int row = j * 16 + ksub * 4 + e;
            const float* xr = &x_lds[row * 20];
            f32x4 xv[4];
            #pragma unroll
            for (int b4 = 0; b4 < 4; b4++)
                xv[b4] = *(const f32x4*)(xr + 4 * b4);
            #pragma unroll
            for (int s = 0; s < 2; s++) {
                const float wv = w[s][j][e];
                #pragma unroll
                for (int b4 = 0; b4 < 4; b4++)
                    #pragma unroll
                    for (int el = 0; el < 4; el++)
                        acc[s][b4 * 4 + el] = fmaf(wv, xv[b4][el], acc[s][b4 * 4 + el]);
            }
        }
    }

    #pragma unroll
    for (int s = 0; s < 2; s++)
        #pragma unroll
        for (int b = 0; b < 16; b++) {
            float v = acc[s][b];
            v += __shfl_xor(v, 1);
            v += __shfl_xor(v, 2);
            acc[s][b] = v;
        }

    if (ksub == 0) {
        #pragma unroll
        for (int s = 0; s < 2; s++) {
            const int oc = q + 128 * s;
            float4* pp = (float4*)(partial + ((long)kc * 256 + oc) * 16);
            pp[0] = make_float4(acc[s][0],  acc[s][1],  acc[s][2],  acc[s][3]);
            pp[1] = make_float4(acc[s][4],  acc[s][5],  acc[s][6],  acc[s][7]);
            pp[2] = make_float4(acc[s][8],  acc[s][9],  acc[s][10], acc[s][11]);
            pp[3] = make_float4(acc[s][12], acc[s][13], acc[s][14], acc[s][15]);
        }
    }
}

__global__ __launch_bounds__(256) void fc_reduce(const float* __restrict__ partial,
                                                 const float* __restrict__ fcb,
                                                 float* __restrict__ out)
{
    __shared__ float red[16][17];
    const int oc = blockIdx.x;
    const int ol = threadIdx.x & 15;
    const int st = threadIdx.x >> 4;
    float s = 0.f;
    #pragma unroll 5
    for (int j = 0; j < 30; j++)
        s += partial[(long)(st + 16 * j) * 4096 + oc * 16 + ol];
    red[st][ol] = s;
    __syncthreads();
    if (threadIdx.x < 16) {
        float tot = fcb[oc];
        #pragma unroll
        for (int k = 0; k < 16; k++) tot += red[k][threadIdx.x];
        out[threadIdx.x * 256 + oc] = fmaxf(tot, 0.f);
    }
}

// ---------------------------------------------------------------------------
extern "C" void kernel_launch(void* const* d_in, const int* in_sizes, int n_in,
                              void* d_out, int out_size, void* d_ws, size_t ws_size,
                              hipStream_t stream) {
    const float* input  = (const float*)d_in[0];
    const int*   coords = (const int*)d_in[1];
    const float* w1 = (const float*)d_in[2];
    const float* b1 = (const float*)d_in[3];
    const float* w2 = (const float*)d_in[4];
    const float* b2 = (const float*)d_in[5];
    const float* w3 = (const float*)d_in[6];
    const float* b3 = (const float*)d_in[7];
    const float* fcw = (const float*)d_in[8];
    const float* fcb = (const float*)d_in[9];
    float* outp = (float*)d_out;

    const int n_active = in_sizes[1] / 3;

    // ---- workspace layout (R6/R8) ----
    char* ws = (char*)d_ws;
    unsigned short* wf1 = (unsigned short*)ws;                    // 18,432 B
    unsigned short* wf2 = wf1 + 9216;                             // 36,864 B
    unsigned short* wf3 = wf2 + 18432;                            // 147,456 B
    unsigned short* inBf    = (unsigned short*)(ws + 204800);     // 31,457,280 B
    unsigned short* pool1bf = (unsigned short*)(ws + 31662080);   //  7,864,320 B
    unsigned short* pool2bf = (unsigned short*)(ws + 39526400);   //  3,932,160 B
    float*          conv3o  = (float*)(ws + 43458560);            //  3,932,160 B
    float*          xT      = (float*)(ws + 47390720);            //  3,932,160 B
    float*          partial = (float*)(ws + 51322880);            //  7,864,320 B

    // zero dense bf16 input, then fused wfrag-prep + scatter-cast.
    hipMemsetAsync(inBf, 0, 31457280, stream);
    const int scatterBlocks = (n_active * 4 + 255) / 256;
    setup_all<<<396 + scatterBlocks, 256, 0, stream>>>(w1, w2, w3, wf1, wf2, wf3,
                                                       coords, input, inBf, n_active);

    // conv1+pool1 fused: (16,96,320,32)->(16,48,160,32) bf16
    // tile 8x16 -> grid 16*6*10 = 960 (3.75 blk/CU), 12 strips / 4 waves
    convpool_mfma<32, 32, 2, 8, 16, 96, 320, 48, 160, 256>
        <<<960, 256, 0, stream>>>(inBf, wf1, b1, pool1bf);

    // conv2+pool2 fused: (16,48,160,32)->(16,24,80,64) bf16
    // tile 8x10, OCB=32 (2 slices) -> grid 16*3*8*2 = 768 (3.0 blk/CU)
    convpool_mfma<32, 64, 2, 8, 10, 48, 160, 24, 80, 256>
        <<<768, 256, 0, stream>>>(pool1bf, wf2, b2, pool2bf);

    // conv3 (unfused, fp32 out): (16,24,80,64)->(16,12,40,128); NL=1
    conv_mfma<64, 128, 1, 24, 80, 12, 40>
        <<<960, 256, 0, stream>>>(pool2bf, wf3, b3, conv3o);

    // pool3+transpose fused (fp32 exact) -> xT
    pool_transpose<<<480, 256, 0, stream>>>(conv3o, xT);

    // FC
    fc_main<<<FC_NKC, 512, 0, stream>>>(xT, fcw, partial);
    fc_reduce<<<256, 256, 0, stream>>>(partial, fcb, outp);
}

// Round 11
// 230.722 us; speedup vs baseline: 1.1062x; 1.0007x over previous
//
#include <hip/hip_runtime.h>

// Problem constants
#define NB 16
#define NH 96
#define NW 320
#define NCIN 32

#define FC_K 61440
#define FC_KB 128          // k per block
#define FC_NKC 480         // 61440/128 chunks

typedef __attribute__((ext_vector_type(8))) short short8;     // 8 bf16 (4 VGPRs)
typedef __attribute__((ext_vector_type(4))) float f32x4;

__device__ inline unsigned short f2bf(float f) {
    union { float f; unsigned int u; } v; v.f = f;
    unsigned int r = v.u + 0x7FFF + ((v.u >> 16) & 1);   // RNE
    return (unsigned short)(r >> 16);
}
__device__ inline float bf2f(unsigned short s) {
    union { unsigned int u; float f; } v; v.u = ((unsigned int)s) << 16; return v.f;
}
__device__ inline unsigned short fhi(float f) {        // exact for bf16-valued floats
    union { float f; unsigned int u; } v; v.f = f; return (unsigned short)(v.u >> 16);
}

// ---------------------------------------------------------------------------
// Fused setup kernel (unchanged): wfrag prep + scatter-cast of active cells.
// ---------------------------------------------------------------------------
__global__ __launch_bounds__(256) void setup_all(const float* __restrict__ w1,
                                                 const float* __restrict__ w2,
                                                 const float* __restrict__ w3,
                                                 unsigned short* __restrict__ f1,
                                                 unsigned short* __restrict__ f2,
                                                 unsigned short* __restrict__ f3,
                                                 const int* __restrict__ coords,
                                                 const float* __restrict__ input,
                                                 unsigned short* __restrict__ inBf,
                                                 int n) {
    if (blockIdx.x < 396) {
        int i = blockIdx.x * 256 + threadIdx.x;
        if (i < 9216) {                       // conv1: IC=32 OC=32 NT=2 KS=1
            int j = i & 7, lane = (i >> 3) & 63, nt = (i >> 9) & 1, tap = i >> 10;
            int ic = ((lane >> 4) * 8) + j, oc = nt * 16 + (lane & 15);
            f1[i] = f2bf(w1[(oc * 32 + ic) * 9 + tap]);
        } else if (i < 27648) {               // conv2: IC=32 OC=64 NT=4 KS=1
            int v = i - 9216;
            int j = v & 7, lane = (v >> 3) & 63, nt = (v >> 9) & 3, tap = v >> 11;
            int ic = ((lane >> 4) * 8) + j, oc = nt * 16 + (lane & 15);
            f2[v] = f2bf(w2[(oc * 32 + ic) * 9 + tap]);
        } else if (i < 101376) {              // conv3: IC=64 OC=128 NT=8 KS=2
            int v = i - 27648;
            int j = v & 7, lane = (v >> 3) & 63, nt = (v >> 9) & 7, kk = v >> 12;
            int tap = kk >> 1, ks = kk & 1;
            int ic = ks * 32 + ((lane >> 4) * 8) + j, oc = nt * 16 + (lane & 15);
            f3[v] = f2bf(w3[(oc * 64 + ic) * 9 + tap]);
        }
    } else {
        int i = (blockIdx.x - 396) * 256 + threadIdx.x;
        if (i >= n * 4) return;
        int ci = i >> 2, q = i & 3;
        int b = coords[ci * 3 + 0], y = coords[ci * 3 + 1], x = coords[ci * 3 + 2];
        long base = ((long)((b * NH + y) * NW + x)) * NCIN + q * 8;
        const float4* src = (const float4*)(input + base);
        float4 v0 = src[0], v1 = src[1];
        union { short8 s8; unsigned short us[8]; } o;
        o.us[0] = f2bf(v0.x); o.us[1] = f2bf(v0.y); o.us[2] = f2bf(v0.z); o.us[3] = f2bf(v0.w);
        o.us[4] = f2bf(v1.x); o.us[5] = f2bf(v1.y); o.us[6] = f2bf(v1.z); o.us[7] = f2bf(v1.w);
        *(short8*)(inBf + base) = o.s8;
    }
}

// ---------------------------------------------------------------------------
// FUSED conv(3x3 s2 p1, MFMA) + maxpool3(s1 p1) + relu, bf16 out (R19 shape).
// ---------------------------------------------------------------------------
template<int IC, int OC, int NTB, int TY, int TX, int IH, int IW, int OH, int OW, int TPB>
__global__ __launch_bounds__(TPB) void convpool_mfma(
    const unsigned short* __restrict__ inPtr,  // NHWC bf16
    const unsigned short* __restrict__ wfrag,  // B-fragments bf16 (NT total tiles)
    const float* __restrict__ bias,
    unsigned short* __restrict__ outBf)        // pooled NHWC bf16
{
    constexpr int KS  = IC / 32;
    constexpr int NT  = OC / 16;               // total oc-tiles in wfrag
    constexpr int OCB = NTB * 16;              // oc per block
    constexpr int NOC = OC / OCB;
    constexpr int CY = TY + 2, CX = TX + 2;
    constexpr int NCELL  = CY * CX;
    constexpr int NSTRIP = (NCELL + 15) / 16;
    constexpr int CSS = OCB + 8;               // LDS cell stride (ushorts)
    constexpr int NTY = OH / TY, NTX = OW / TX;
    constexpr int NWAVE = TPB / 64;

    __shared__ __align__(16) unsigned short cs[NCELL * CSS];

    int bid = blockIdx.x;
    const int ocsel = bid % NOC; bid /= NOC;
    const int txi = bid % NTX;   bid /= NTX;
    const int tyi = bid % NTY;
    const int b   = bid / NTY;
    const int y0 = tyi * TY, x0 = txi * TX;

    const int t = threadIdx.x;
    const int wid = t >> 6, lane = t & 63, quad = lane >> 4, lm = lane & 15;

    short8 zero8;
    #pragma unroll
    for (int j = 0; j < 8; j++) zero8[j] = 0;

    // ---------------- phase 1: conv halo -> LDS bf16 ----------------
    for (int s = wid; s < NSTRIP; s += NWAVE) {
        int idx = s * 16 + lm;
        if (idx > NCELL - 1) idx = NCELL - 1;          // clamp dummy lanes
        const int oy = y0 - 1 + idx / CX;
        const int ox = x0 - 1 + idx % CX;
        const int iy0 = oy * 2 - 1, ix0 = ox * 2 - 1;

        int cell[9]; bool okb[9];
        #pragma unroll
        for (int t9 = 0; t9 < 9; t9++) {
            const int iy = iy0 + t9 / 3;
            const int ix = ix0 + t9 % 3;
            const bool ok = (iy >= 0) && (iy < IH) && (ix >= 0) && (ix < IW);
            cell[t9] = ok ? ((b * IH + iy) * IW + ix) : 0;
            okb[t9] = ok;
        }

        f32x4 acc[NTB][2];
        #pragma unroll
        for (int nl = 0; nl < NTB; nl++)
            #pragma unroll
            for (int pp = 0; pp < 2; pp++)
                acc[nl][pp] = (f32x4){0.f, 0.f, 0.f, 0.f};

        #pragma unroll
        for (int ks = 0; ks < KS; ks++) {
            short8 av[9];
            #pragma unroll
            for (int t9 = 0; t9 < 9; t9++) {
                short8 v = *(const short8*)(inPtr + (long)cell[t9] * IC + ks * 32 + quad * 8);
                av[t9] = okb[t9] ? v : zero8;
            }
            #pragma unroll
            for (int nl = 0; nl < NTB; nl++) {
                const int nt = ocsel * NTB + nl;
                #pragma unroll
                for (int t9 = 0; t9 < 9; t9++) {
                    short8 bf = *(const short8*)(wfrag + (((t9 * KS + ks) * NT + nt) * 64 + lane) * 8);
                    if (t9 & 1) acc[nl][1] = __builtin_amdgcn_mfma_f32_16x16x32_bf16(av[t9], bf, acc[nl][1], 0, 0, 0);
                    else        acc[nl][0] = __builtin_amdgcn_mfma_f32_16x16x32_bf16(av[t9], bf, acc[nl][0], 0, 0, 0);
                }
            }
        }

        // D-store to LDS: lane holds rows quad*4+reg, col lm
        #pragma unroll
        for (int nl = 0; nl < NTB; nl++) {
            const float bv = bias[(ocsel * NTB + nl) * 16 + lm];
            #pragma unroll
            for (int reg = 0; reg < 4; reg++) {
                const int ci = s * 16 + quad * 4 + reg;
                if (ci < NCELL)
                    cs[ci * CSS + nl * 16 + lm] = f2bf(acc[nl][0][reg] + acc[nl][1][reg] + bv);
            }
        }
    }
    __syncthreads();

    // ---------------- phase 2: pool 3x3 s1 p1 + relu -> global bf16 ----------------
    constexpr int NTASK = TY * TX * (OCB / 8);
    for (int u = t; u < NTASK; u += TPB) {
        const int c8 = u & (OCB / 8 - 1);
        const int px = (u / (OCB / 8)) % TX;
        const int py = u / ((OCB / 8) * TX);
        const int gy = y0 + py, gx = x0 + px;

        float m[8];
        #pragma unroll
        for (int e = 0; e < 8; e++) m[e] = 0.f;        // relu floor

        #pragma unroll
        for (int dy = -1; dy <= 1; dy++) {
            const int yy = gy + dy;
            if (yy < 0 || yy >= OH) continue;
            #pragma unroll
            for (int dx = -1; dx <= 1; dx++) {
                const int xx = gx + dx;
                if (xx < 0 || xx >= OW) continue;
                const int ci = (py + dy + 1) * CX + (px + dx + 1);
                short8 v = *(const short8*)(&cs[ci * CSS + c8 * 8]);
                #pragma unroll
                for (int e = 0; e < 8; e++)
                    m[e] = fmaxf(m[e], bf2f((unsigned short)v[e]));
            }
        }
        union { short8 s8; unsigned short us[8]; } o;
        #pragma unroll
        for (int e = 0; e < 8; e++) o.us[e] = fhi(m[e]);   // exact repack
        *(short8*)(outBf + ((long)((b * OH + gy) * OW + gx)) * OC + ocsel * OCB + c8 * 8) = o.s8;
    }
}

// ---------------------------------------------------------------------------
// Implicit-GEMM conv (unfused; used for conv3 only). Unchanged.
// ---------------------------------------------------------------------------
template<int IC, int OC, int NL, int IH, int IW, int OH, int OW>
__global__ __launch_bounds__(256) void conv_mfma(
    const unsigned short* __restrict__ inPtr,
    const unsigned short* __restrict__ wfrag,
    const float* __restrict__ bias,
    float* __restrict__ out)
{
    constexpr int KS = IC / 32;
    constexpr int NT = OC / 16;
    constexpr int NG = NT / NL;
    constexpr int NSTRIPS = NB * OH * OW / 16;

    const int wid  = (blockIdx.x * 256 + threadIdx.x) >> 6;
    const int lane = threadIdx.x & 63;
    const int ntb  = (wid % NG) * NL;
    const int s    = wid / NG;
    if (s >= NSTRIPS) return;
    const int quad = lane >> 4;
    const int lm   = lane & 15;

    const int p0 = s * 16;
    const int posA = p0 + lm;
    const int b  = posA / (OH * OW);
    const int rr = posA % (OH * OW);
    const int oy = rr / OW, ox = rr % OW;
    const int iy0 = oy * 2 - 1, ix0 = ox * 2 - 1;

    int cell[9];
    bool okb[9];
    #pragma unroll
    for (int t9 = 0; t9 < 9; t9++) {
        const int iy = iy0 + t9 / 3;
        const int ix = ix0 + t9 % 3;
        const bool ok = (iy >= 0) && (iy < IH) && (ix >= 0) && (ix < IW);
        cell[t9] = ok ? ((b * IH + iy) * IW + ix) : 0;
        okb[t9] = ok;
    }

    short8 zero8;
    #pragma unroll
    for (int j = 0; j < 8; j++) zero8[j] = 0;

    f32x4 acc[NL][2];
    #pragma unroll
    for (int nl = 0; nl < NL; nl++)
        #pragma unroll
        for (int pp = 0; pp < 2; pp++)
            acc[nl][pp] = (f32x4){0.f, 0.f, 0.f, 0.f};

    #pragma unroll 1
    for (int ks = 0; ks < KS; ks++) {
        short8 av[9];
        #pragma unroll
        for (int t9 = 0; t9 < 9; t9++) {
            short8 v = *(const short8*)(inPtr + (long)cell[t9] * IC + ks * 32 + quad * 8);
            av[t9] = okb[t9] ? v : zero8;
        }
        #pragma unroll
        for (int nl = 0; nl < NL; nl++) {
            #pragma unroll
            for (int t9 = 0; t9 < 9; t9++) {
                short8 bf = *(const short8*)(wfrag + (((t9 * KS + ks) * NT + ntb + nl) * 64 + lane) * 8);
                if (t9 & 1) acc[nl][1] = __builtin_amdgcn_mfma_f32_16x16x32_bf16(av[t9], bf, acc[nl][1], 0, 0, 0);
                else        acc[nl][0] = __builtin_amdgcn_mfma_f32_16x16x32_bf16(av[t9], bf, acc[nl][0], 0, 0, 0);
            }
        }
    }

    const long rowBase = (long)p0 + quad * 4;
    #pragma unroll
    for (int nl = 0; nl < NL; nl++) {
        const int oc = (ntb + nl) * 16 + lm;
        const float bv = bias[oc];
        #pragma unroll
        for (int reg = 0; reg < 4; reg++)
            out[(rowBase + reg) * OC + oc] = acc[nl][0][reg] + acc[nl][1][reg] + bv;
    }
}

// ---------------------------------------------------------------------------
// FUSED maxpool3+relu (fp32 exact) + transpose for the FC (unchanged).
// ---------------------------------------------------------------------------
__global__ __launch_bounds__(256) void pool_transpose(const float* __restrict__ conv3o,
                                                      float* __restrict__ xT) {
    __shared__ float tile_s[8 * 16 * 17];     // [c_l][pos_l][b(pad 17)]
    const int pt = blockIdx.x % 30;
    const int ct = blockIdx.x / 30;           // 0..15
    const int pos0 = pt * 16, c0 = ct * 8;
    const int t = threadIdx.x;
    {
        const int b = t >> 4, pl = t & 15;
        const int pos = pos0 + pl;
        const int py = pos / 40, px = pos % 40;
        float4 m0 = make_float4(0.f, 0.f, 0.f, 0.f);   // relu floor
        float4 m1 = make_float4(0.f, 0.f, 0.f, 0.f);
        #pragma unroll
        for (int dy = -1; dy <= 1; dy++) {
            const int yy = py + dy;
            if (yy < 0 || yy >= 12) continue;
            #pragma unroll
            for (int dx = -1; dx <= 1; dx++) {
                const int xx = px + dx;
                if (xx < 0 || xx >= 40) continue;
                const float4* src = (const float4*)(conv3o + ((long)((b * 12 + yy) * 40 + xx)) * 128 + c0);
                float4 v0 = src[0], v1 = src[1];
                m0.x = fmaxf(m0.x, v0.x); m0.y = fmaxf(m0.y, v0.y);
                m0.z = fmaxf(m0.z, v0.z); m0.w = fmaxf(m0.w, v0.w);
                m1.x = fmaxf(m1.x, v1.x); m1.y = fmaxf(m1.y, v1.y);
                m1.z = fmaxf(m1.z, v1.z); m1.w = fmaxf(m1.w, v1.w);
            }
        }
        tile_s[(0 * 16 + pl) * 17 + b] = m0.x;
        tile_s[(1 * 16 + pl) * 17 + b] = m0.y;
        tile_s[(2 * 16 + pl) * 17 + b] = m0.z;
        tile_s[(3 * 16 + pl) * 17 + b] = m0.w;
        tile_s[(4 * 16 + pl) * 17 + b] = m1.x;
        tile_s[(5 * 16 + pl) * 17 + b] = m1.y;
        tile_s[(6 * 16 + pl) * 17 + b] = m1.z;
        tile_s[(7 * 16 + pl) * 17 + b] = m1.w;
    }
    __syncthreads();
    {
        const int w = t >> 6, l = t & 63;
        const int pl2 = l >> 2, b4 = l & 3;
        #pragma unroll
        for (int i = 0; i < 2; i++) {
            int cl = w + 4 * i;
            const float* ls = &tile_s[(cl * 16 + pl2) * 17 + 4 * b4];
            float4 v = make_float4(ls[0], ls[1], ls[2], ls[3]);
            *(float4*)(xT + ((long)(c0 + cl) * 480 + pos0 + pl2) * 16 + 4 * b4) = v;
        }
    }
}

// ---------------------------------------------------------------------------
// FC main v11 (R20): asm-enforced 16-deep weight load pipeline.
// The full FC evidence chain: v3 VGPR=84 and v8 VGPR=44 (compiler refuses
// register preloads -- sinks/splits them into the loop, ~1-2 loads in
// flight, 1.2-1.9 TB/s); v9 PIN4 fence null (one-point materialization
// doesn't stop downstream RE-loading); v10 DMA hit the wave-uniform-dest
// legalization trap (WRITE_SIZE=73MB). The untried lever: take issue order
// away from the compiler. asm volatile global_load_dwordx4 is opaque --
// it cannot be sunk, split, or rematerialized (the compiler does not know
// how the value was produced), and consecutive volatile asms keep program
// order. All 16 loads issue BEFORE the x-stage + __syncthreads (whose
// built-in vmcnt(0) drain is exactly the single wait we want): 256 B/thread
// x 8 waves = 128 KB/CU in flight >> 22 KB BW*latency product.
// Belt-and-suspenders: s_waitcnt vmcnt(0) asm with all 16 values as "+v"
// (every use data-depends on it) + sched_barrier(0) per rule #18.
// launch_bounds(512) WITHOUT min-waves: VGPR ~130 by construction, no spill.
// Compute mapping/accumulation order/partial layout = v7 (passing numerics).
// ---------------------------------------------------------------------------
#define WLOAD(dst_, addr_) \
    asm volatile("global_load_dwordx4 %0, %1, off" : "=v"(dst_) : "v"(addr_))

__global__ __launch_bounds__(512) void fc_main(const float* __restrict__ xT,
                                               const float* __restrict__ fw,
                                               float* __restrict__ partial)
{
    __shared__ float x_lds[128 * 20];
    const int kc   = blockIdx.x;
    const int t    = threadIdx.x;
    const int q    = t >> 2;
    const int ksub = t & 3;
    const int k0   = kc * FC_KB;

    // ---- issue ALL 16 weight loads via opaque asm (cannot be sunk) ----
    const float* wr0 = fw + (long)q * FC_K + k0 + ksub * 4;
    const float* wr1 = wr0 + (long)128 * FC_K;
    f32x4 w[2][8];
    WLOAD(w[0][0], wr0 +   0); WLOAD(w[0][1], wr0 +  16);
    WLOAD(w[0][2], wr0 +  32); WLOAD(w[0][3], wr0 +  48);
    WLOAD(w[0][4], wr0 +  64); WLOAD(w[0][5], wr0 +  80);
    WLOAD(w[0][6], wr0 +  96); WLOAD(w[0][7], wr0 + 112);
    WLOAD(w[1][0], wr1 +   0); WLOAD(w[1][1], wr1 +  16);
    WLOAD(w[1][2], wr1 +  32); WLOAD(w[1][3], wr1 +  48);
    WLOAD(w[1][4], wr1 +  64); WLOAD(w[1][5], wr1 +  80);
    WLOAD(w[1][6], wr1 +  96); WLOAD(w[1][7], wr1 + 112);

    // ---- stage x[128][16] into LDS (overlaps the 16 in-flight loads) ----
    {
        const int kr = t >> 2, b4 = t & 3;
        *(float4*)(&x_lds[kr * 20 + b4 * 4]) =
            *(const float4*)(xT + ((long)(k0 + kr)) * 16 + b4 * 4);
    }
    __syncthreads();   // compiler's pre-barrier vmcnt(0) drains weights+x

    // ---- hard wait + anti-hoist fence: every w use data-depends on this ----
    asm volatile("s_waitcnt vmcnt(0)"
        : "+v"(w[0][0]), "+v"(w[0][1]), "+v"(w[0][2]), "+v"(w[0][3]),
          "+v"(w[0][4]), "+v"(w[0][5]), "+v"(w[0][6]), "+v"(w[0][7]),
          "+v"(w[1][0]), "+v"(w[1][1]), "+v"(w[1][2]), "+v"(w[1][3]),
          "+v"(w[1][4]), "+v"(w[1][5]), "+v"(w[1][6]), "+v"(w[1][7]));
    __builtin_amdgcn_sched_barrier(0);

    float acc[2][16];
    #pragma unroll
    for (int s = 0; s < 2; s++)
        #pragma unroll
        for (int b = 0; b < 16; b++) acc[s][b] = 0.f;

    #pragma unroll
    for (int j = 0; j < 8; j++) {
        #pragma unroll
        for (int e = 0; e < 4; e++) {
            const int row = j * 16 + ksub * 4 + e;
            const float* xr = &x_lds[row * 20];
            f32x4 xv[4];
            #pragma unroll
            for (int b4 = 0; b4 < 4; b4++)
                xv[b4] = *(const f32x4*)(xr + 4 * b4);
            #pragma unroll
            for (int s = 0; s < 2; s++) {
                const float wv = w[s][j][e];
                #pragma unroll
                for (int b4 = 0; b4 < 4; b4++)
                    #pragma unroll
                    for (int el = 0; el < 4; el++)
                        acc[s][b4 * 4 + el] = fmaf(wv, xv[b4][el], acc[s][b4 * 4 + el]);
            }
        }
    }

    #pragma unroll
    for (int s = 0; s < 2; s++)
        #pragma unroll
        for (int b = 0; b < 16; b++) {
            float v = acc[s][b];
            v += __shfl_xor(v, 1);
            v += __shfl_xor(v, 2);
            acc[s][b] = v;
        }

    if (ksub == 0) {
        #pragma unroll
        for (int s = 0; s < 2; s++) {
            const int oc = q + 128 * s;
            float4* pp = (float4*)(partial + ((long)kc * 256 + oc) * 16);
            pp[0] = make_float4(acc[s][0],  acc[s][1],  acc[s][2],  acc[s][3]);
            pp[1] = make_float4(acc[s][4],  acc[s][5],  acc[s][6],  acc[s][7]);
            pp[2] = make_float4(acc[s][8],  acc[s][9],  acc[s][10], acc[s][11]);
            pp[3] = make_float4(acc[s][12], acc[s][13], acc[s][14], acc[s][15]);
        }
    }
}

__global__ __launch_bounds__(256) void fc_reduce(const float* __restrict__ partial,
                                                 const float* __restrict__ fcb,
                                                 float* __restrict__ out)
{
    __shared__ float red[16][17];
    const int oc = blockIdx.x;
    const int ol = threadIdx.x & 15;
    const int st = threadIdx.x >> 4;
    float s = 0.f;
    #pragma unroll 5
    for (int j = 0; j < 30; j++)
        s += partial[(long)(st + 16 * j) * 4096 + oc * 16 + ol];
    red[st][ol] = s;
    __syncthreads();
    if (threadIdx.x < 16) {
        float tot = fcb[oc];
        #pragma unroll
        for (int k = 0; k < 16; k++) tot += red[k][threadIdx.x];
        out[threadIdx.x * 256 + oc] = fmaxf(tot, 0.f);
    }
}

// ---------------------------------------------------------------------------
extern "C" void kernel_launch(void* const* d_in, const int* in_sizes, int n_in,
                              void* d_out, int out_size, void* d_ws, size_t ws_size,
                              hipStream_t stream) {
    const float* input  = (const float*)d_in[0];
    const int*   coords = (const int*)d_in[1];
    const float* w1 = (const float*)d_in[2];
    const float* b1 = (const float*)d_in[3];
    const float* w2 = (const float*)d_in[4];
    const float* b2 = (const float*)d_in[5];
    const float* w3 = (const float*)d_in[6];
    const float* b3 = (const float*)d_in[7];
    const float* fcw = (const float*)d_in[8];
    const float* fcb = (const float*)d_in[9];
    float* outp = (float*)d_out;

    const int n_active = in_sizes[1] / 3;

    // ---- workspace layout (R6/R8) ----
    char* ws = (char*)d_ws;
    unsigned short* wf1 = (unsigned short*)ws;                    // 18,432 B
    unsigned short* wf2 = wf1 + 9216;                             // 36,864 B
    unsigned short* wf3 = wf2 + 18432;                            // 147,456 B
    unsigned short* inBf    = (unsigned short*)(ws + 204800);     // 31,457,280 B
    unsigned short* pool1bf = (unsigned short*)(ws + 31662080);   //  7,864,320 B
    unsigned short* pool2bf = (unsigned short*)(ws + 39526400);   //  3,932,160 B
    float*          conv3o  = (float*)(ws + 43458560);            //  3,932,160 B
    float*          xT      = (float*)(ws + 47390720);            //  3,932,160 B
    float*          partial = (float*)(ws + 51322880);            //  7,864,320 B

    // zero dense bf16 input, then fused wfrag-prep + scatter-cast.
    hipMemsetAsync(inBf, 0, 31457280, stream);
    const int scatterBlocks = (n_active * 4 + 255) / 256;
    setup_all<<<396 + scatterBlocks, 256, 0, stream>>>(w1, w2, w3, wf1, wf2, wf3,
                                                       coords, input, inBf, n_active);

    // conv1+pool1 fused: (16,96,320,32)->(16,48,160,32) bf16
    convpool_mfma<32, 32, 2, 8, 16, 96, 320, 48, 160, 256>
        <<<960, 256, 0, stream>>>(inBf, wf1, b1, pool1bf);

    // conv2+pool2 fused: (16,48,160,32)->(16,24,80,64) bf16
    convpool_mfma<32, 64, 2, 8, 10, 48, 160, 24, 80, 256>
        <<<768, 256, 0, stream>>>(pool1bf, wf2, b2, pool2bf);

    // conv3 (unfused, fp32 out): (16,24,80,64)->(16,12,40,128); NL=1
    conv_mfma<64, 128, 1, 24, 80, 12, 40>
        <<<960, 256, 0, stream>>>(pool2bf, wf3, b3, conv3o);

    // pool3+transpose fused (fp32 exact) -> xT
    pool_transpose<<<480, 256, 0, stream>>>(conv3o, xT);

    // FC (asm-pipelined weight stream)
    fc_main<<<FC_NKC, 512, 0, stream>>>(xT, fcw, partial);
    fc_reduce<<<256, 256, 0, stream>>>(partial, fcb, outp);
}